// Round 6
// baseline (511.604 us; speedup 1.0000x reference)
//
#include <hip/hip_runtime.h>

#define IN_F 32
#define HID 64
#define OUTF 16
#define EPW 16                     // edges per wave per iteration (one MFMA M-tile)
#define ORD_NEG_INF 0x007FFFFFu    // ordenc(-inf)

typedef _Float16 v8h __attribute__((ext_vector_type(8)));
typedef float v4f __attribute__((ext_vector_type(4)));

// monotone float -> uint map so unsigned max == float max
__device__ __forceinline__ unsigned ordenc(float v) {
  unsigned b = __float_as_uint(v);
  return (b & 0x80000000u) ? ~b : (b | 0x80000000u);
}
__device__ __forceinline__ float orddec(unsigned u) {
  unsigned b = (u & 0x80000000u) ? (u & 0x7FFFFFFFu) : ~u;
  return __uint_as_float(b);
}

__global__ __launch_bounds__(256) void init_agg_kernel(unsigned* __restrict__ agg, int n) {
  int i = blockIdx.x * blockDim.x + threadIdx.x;
  if (i < n) agg[i] = ORD_NEG_INF;
}

// Per-node precompute: P[n] = x[n] @ (W1A - W1B) + b1,  Q[n] = x[n] @ W1B
__global__ __launch_bounds__(256) void node_pre_kernel(
    const float* __restrict__ x, const float* __restrict__ W1,
    const float* __restrict__ b1, float* __restrict__ P, float* __restrict__ Q, int N)
{
  const int lane = threadIdx.x & 63;
  float w1d[IN_F], w1b[IN_F];
#pragma unroll
  for (int c = 0; c < IN_F; ++c) {
    w1b[c] = W1[(IN_F + c) * HID + lane];
    w1d[c] = W1[c * HID + lane] - w1b[c];
  }
  const float b1v = b1[lane];
  int gw = __builtin_amdgcn_readfirstlane((blockIdx.x << 2) | (threadIdx.x >> 6));
  const int nwaves = gridDim.x << 2;
  for (int n = gw; n < N; n += nwaves) {
    float p = b1v, q = 0.f;
#pragma unroll
    for (int c = 0; c < IN_F; ++c) {
      float xv = x[n * IN_F + c];
      p = fmaf(xv, w1d[c], p);
      q = fmaf(xv, w1b[c], q);
    }
    P[n * HID + lane] = p;
    Q[n * HID + lane] = q;
  }
}

// Edge kernel: MFMA layer2, atomics issued straight from D-layout,
// test-before-atomic filter (safe under monotone max).
__global__ __launch_bounds__(256) void edge_kernel(
    const int* __restrict__ ei,            // [2, E]
    const float* __restrict__ ea,          // [E, 3]
    const float* __restrict__ W1,          // [67, 64] (rows 64..66 used)
    const float* __restrict__ W2,          // [64, 64]
    const float* __restrict__ P,           // [N, 64]
    const float* __restrict__ Q,           // [N, 64]
    unsigned* __restrict__ agg,            // [N, 64] ord-encoded (no b2)
    int E)
{
  __shared__ __align__(16) _Float16 hB[4][EPW][72];  // [wave][edge][ch]

  const int wave = threadIdx.x >> 6;
  const int lane = threadIdx.x & 63;
  const int quad = lane >> 4;
  const int eidx = lane & 15;

  // A-operand: W2^T fragments, fp16, loop-invariant.
  v8h a_frag[4][2];
#pragma unroll
  for (int t = 0; t < 4; ++t)
#pragma unroll
    for (int ks = 0; ks < 2; ++ks)
#pragma unroll
      for (int j = 0; j < 8; ++j)
        a_frag[t][ks][j] = (_Float16)W2[(ks * 32 + quad * 8 + j) * HID + t * 16 + eidx];

  const float w1c0 = W1[(2 * IN_F + 0) * HID + lane];
  const float w1c1 = W1[(2 * IN_F + 1) * HID + lane];
  const float w1c2 = W1[(2 * IN_F + 2) * HID + lane];

  const int gwave = __builtin_amdgcn_readfirstlane((blockIdx.x << 2) | wave);
  const int stride = gridDim.x * 4 * EPW;

  int scur[EPW], dcur[EPW];              // wave-uniform (scalar) indices
  float pv[EPW], qv[EPW];
  float ea0[EPW], ea1[EPW], ea2[EPW];

  int e0 = gwave * EPW;
  // ---- preamble: indices, gathers, ea for iteration 0 ----
#pragma unroll
  for (int i = 0; i < EPW; ++i) {
    int e = e0 + i;
    bool v = e < E;
    int ec = v ? e : 0;
    scur[i] = ei[ec];
    dcur[i] = v ? ei[(size_t)E + ec] : 0;
  }
#pragma unroll
  for (int i = 0; i < EPW; ++i) {
    pv[i] = P[dcur[i] * HID + lane];
    qv[i] = Q[scur[i] * HID + lane];
  }
#pragma unroll
  for (int i = 0; i < EPW; ++i) {
    int e = min(e0 + i, E - 1);
    ea0[i] = ea[e * 3 + 0]; ea1[i] = ea[e * 3 + 1]; ea2[i] = ea[e * 3 + 2];
  }

  while (e0 < E) {
    const int e1 = e0 + stride;

    // ---- per-lane dst for atomic layout (edge = eidx) + validity ----
    const bool vte = (e0 + eidx) < E;
    const int  dte = ei[(size_t)E + min(e0 + eidx, E - 1)];

    // ---- layer 1 (lane = channel) -> fp16 -> hB[edge][ch] ----
#pragma unroll
    for (int i = 0; i < EPW; ++i) {
      float pre = pv[i] + qv[i];
      pre = fmaf(ea0[i], w1c0, pre);
      pre = fmaf(ea1[i], w1c1, pre);
      pre = fmaf(ea2[i], w1c2, pre);
      hB[wave][i][lane] = (_Float16)fmaxf(pre, 0.f);
    }

    // ---- filter loads: current agg values in D-layout (L2/L3 cached) ----
    unsigned curu[4][4];
#pragma unroll
    for (int t = 0; t < 4; ++t)
#pragma unroll
      for (int r = 0; r < 4; ++r)
        curu[t][r] = agg[(size_t)dte * HID + t * 16 + quad * 4 + r];

    // ---- prefetch next iteration ----
#pragma unroll
    for (int i = 0; i < EPW; ++i) {
      int e = e1 + i;
      bool v = e < E;
      int ec = v ? e : 0;
      scur[i] = ei[ec];
      dcur[i] = v ? ei[(size_t)E + ec] : 0;
    }
#pragma unroll
    for (int i = 0; i < EPW; ++i) {
      pv[i] = P[dcur[i] * HID + lane];
      qv[i] = Q[scur[i] * HID + lane];
    }
#pragma unroll
    for (int i = 0; i < EPW; ++i) {
      int e = min(e1 + i, E - 1);
      ea0[i] = ea[e * 3 + 0]; ea1[i] = ea[e * 3 + 1]; ea2[i] = ea[e * 3 + 2];
    }

    __builtin_amdgcn_wave_barrier();

    // ---- layer 2: 8x mfma. B-frag: hB[edge=eidx][k=ks*32+quad*8 ..+7] ----
    const v8h bf0 = *(const v8h*)&hB[wave][eidx][quad * 8];
    const v8h bf1 = *(const v8h*)&hB[wave][eidx][32 + quad * 8];
    v4f acc[4];
#pragma unroll
    for (int t = 0; t < 4; ++t) {
      acc[t] = (v4f){0.f, 0.f, 0.f, 0.f};
      acc[t] = __builtin_amdgcn_mfma_f32_16x16x32_f16(a_frag[t][0], bf0, acc[t], 0, 0, 0);
      acc[t] = __builtin_amdgcn_mfma_f32_16x16x32_f16(a_frag[t][1], bf1, acc[t], 0, 0, 0);
    }

    // ---- filtered max-scatter straight from D-layout ----
    // D[m][n]: col=eidx (edge), row=quad*4+r in tile t -> channel t*16+quad*4+r
#pragma unroll
    for (int t = 0; t < 4; ++t)
#pragma unroll
      for (int r = 0; r < 4; ++r) {
        unsigned enc = ordenc(acc[t][r]);
        if (vte && enc > curu[t][r])
          atomicMax(&agg[(size_t)dte * HID + t * 16 + quad * 4 + r], enc);
      }

    e0 = e1;
  }
}

// 16 nodes per block: decode agg (empty -> 0, else +b2), out = sigmoid(agg @ Wo + bo)
__global__ __launch_bounds__(256) void out_kernel(
    const unsigned* __restrict__ agg,
    const float* __restrict__ b2,  // [64] (deferred from edge kernel)
    const float* __restrict__ Wo, const float* __restrict__ bo,
    float* __restrict__ out, int N)
{
  __shared__ float Wos[HID * OUTF];
  __shared__ float bos[OUTF];
  __shared__ float b2s[HID];
  __shared__ float aggs[16][HID + 1];

  for (int i = threadIdx.x; i < HID * OUTF; i += 256) Wos[i] = Wo[i];
  if (threadIdx.x < OUTF) bos[threadIdx.x] = bo[threadIdx.x];
  if (threadIdx.x < HID) b2s[threadIdx.x] = b2[threadIdx.x];
  __syncthreads();

  const int nodeBase = blockIdx.x * 16;
  {
    int ln = threadIdx.x >> 4;
    int k0 = (threadIdx.x & 15) * 4;
    int n = nodeBase + ln;
    if (n < N) {
      const uint4 u = *(const uint4*)&agg[n * HID + k0];
      aggs[ln][k0 + 0] = (u.x == ORD_NEG_INF) ? 0.f : orddec(u.x) + b2s[k0 + 0];
      aggs[ln][k0 + 1] = (u.y == ORD_NEG_INF) ? 0.f : orddec(u.y) + b2s[k0 + 1];
      aggs[ln][k0 + 2] = (u.z == ORD_NEG_INF) ? 0.f : orddec(u.z) + b2s[k0 + 2];
      aggs[ln][k0 + 3] = (u.w == ORD_NEG_INF) ? 0.f : orddec(u.w) + b2s[k0 + 3];
    }
  }
  __syncthreads();
  {
    int ln = threadIdx.x >> 4;
    int o = threadIdx.x & 15;
    int n = nodeBase + ln;
    if (n < N) {
      float acc = bos[o];
#pragma unroll
      for (int k = 0; k < HID; ++k) acc = fmaf(aggs[ln][k], Wos[k * OUTF + o], acc);
      out[n * OUTF + o] = 1.f / (1.f + __expf(-acc));
    }
  }
}

extern "C" void kernel_launch(void* const* d_in, const int* in_sizes, int n_in,
                              void* d_out, int out_size, void* d_ws, size_t ws_size,
                              hipStream_t stream) {
  const float* x  = (const float*)d_in[0];
  const int*   ei = (const int*)d_in[1];
  const float* ea = (const float*)d_in[2];
  const float* W1 = (const float*)d_in[3];
  const float* b1 = (const float*)d_in[4];
  const float* W2 = (const float*)d_in[5];
  const float* b2 = (const float*)d_in[6];
  const float* Wo = (const float*)d_in[7];
  const float* bo = (const float*)d_in[8];
  float* out = (float*)d_out;

  const int N = in_sizes[0] / IN_F;   // 50000
  const int E = in_sizes[1] / 2;      // 1600000

  float*    Pp  = (float*)d_ws;
  float*    Qp  = Pp + (size_t)N * HID;
  unsigned* agg = (unsigned*)(Qp + (size_t)N * HID);

  const int ntot = N * HID;
  init_agg_kernel<<<(ntot + 255) / 256, 256, 0, stream>>>(agg, ntot);
  node_pre_kernel<<<512, 256, 0, stream>>>(x, W1, b1, Pp, Qp, N);
  edge_kernel<<<2048, 256, 0, stream>>>(ei, ea, W1, W2, Pp, Qp, agg, E);
  out_kernel<<<(N + 15) / 16, 256, 0, stream>>>(agg, b2, Wo, bo, out, N);
}

// Round 7
// 333.983 us; speedup vs baseline: 1.5318x; 1.5318x over previous
//
#include <hip/hip_runtime.h>

#define IN_F 32
#define HID 64
#define OUTF 16
#define BCAP 64                    // bucket capacity (records per dst node)
#define OVF_CAP 262144             // overflow list capacity (expected use: 0)
#define ORD_NEG_INF 0x007FFFFFu    // ordenc(-inf)

typedef _Float16 v8h __attribute__((ext_vector_type(8)));
typedef float v4f __attribute__((ext_vector_type(4)));

// monotone float -> uint map so unsigned max == float max
__device__ __forceinline__ unsigned ordenc(float v) {
  unsigned b = __float_as_uint(v);
  return (b & 0x80000000u) ? ~b : (b | 0x80000000u);
}
__device__ __forceinline__ float orddec(unsigned u) {
  unsigned b = (u & 0x80000000u) ? (u & 0x7FFFFFFFu) : ~u;
  return __uint_as_float(b);
}

// Per-node precompute: P[n] = x[n] @ (W1A - W1B) + b1,  Q[n] = x[n] @ W1B
__global__ __launch_bounds__(256) void node_pre_kernel(
    const float* __restrict__ x, const float* __restrict__ W1,
    const float* __restrict__ b1, float* __restrict__ P, float* __restrict__ Q, int N)
{
  const int lane = threadIdx.x & 63;
  float w1d[IN_F], w1b[IN_F];
#pragma unroll
  for (int c = 0; c < IN_F; ++c) {
    w1b[c] = W1[(IN_F + c) * HID + lane];
    w1d[c] = W1[c * HID + lane] - w1b[c];
  }
  const float b1v = b1[lane];
  int gw = __builtin_amdgcn_readfirstlane((blockIdx.x << 2) | (threadIdx.x >> 6));
  const int nwaves = gridDim.x << 2;
  for (int n = gw; n < N; n += nwaves) {
    float p = b1v, q = 0.f;
#pragma unroll
    for (int c = 0; c < IN_F; ++c) {
      float xv = x[n * IN_F + c];
      p = fmaf(xv, w1d[c], p);
      q = fmaf(xv, w1b[c], q);
    }
    P[n * HID + lane] = p;
    Q[n * HID + lane] = q;
  }
}

// Scatter edges into per-dst buckets: rec = {src_bits, ea0, ea1, ea2}
__global__ __launch_bounds__(256) void scatter_kernel(
    const int* __restrict__ ei, const float* __restrict__ ea,
    float4* __restrict__ rec, int* __restrict__ cnt,
    int* __restrict__ ovf, int* __restrict__ ovf_cnt, int E)
{
  int e = blockIdx.x * blockDim.x + threadIdx.x;
  if (e >= E) return;
  int s = ei[e];
  int d = ei[(size_t)E + e];
  float a0 = ea[e * 3 + 0], a1 = ea[e * 3 + 1], a2 = ea[e * 3 + 2];
  int pos = atomicAdd(&cnt[d], 1);
  if (pos < BCAP) {
    rec[(size_t)d * BCAP + pos] = make_float4(__int_as_float(s), a0, a1, a2);
  } else {
    int oi = atomicAdd(ovf_cnt, 1);
    if (oi < OVF_CAP) ovf[oi] = e;
  }
}

// One wave per dst node: MFMA layer2 over 16-edge tiles, running max in
// D-layout registers, one LDS transpose + one coalesced agg-row store per dst.
// Zero global atomics.
__global__ __launch_bounds__(256) void bucket_kernel(
    const float4* __restrict__ rec, const int* __restrict__ cnt,
    const float* __restrict__ W1, const float* __restrict__ W2,
    const float* __restrict__ P, const float* __restrict__ Q,
    unsigned* __restrict__ agg, int N)
{
  __shared__ __align__(16) _Float16 hB[4][16][72];  // [wave][edge][ch]
  __shared__ unsigned rowS[4][HID];                 // [wave][ch]

  const int wave = threadIdx.x >> 6;
  const int lane = threadIdx.x & 63;
  const int quad = lane >> 4;
  const int eidx = lane & 15;

  // A-operand: W2^T fragments, fp16, loop-invariant (verified in R5).
  v8h a_frag[4][2];
#pragma unroll
  for (int t = 0; t < 4; ++t)
#pragma unroll
    for (int ks = 0; ks < 2; ++ks)
#pragma unroll
      for (int j = 0; j < 8; ++j)
        a_frag[t][ks][j] = (_Float16)W2[(ks * 32 + quad * 8 + j) * HID + t * 16 + eidx];

  const float w1c0 = W1[(2 * IN_F + 0) * HID + lane];
  const float w1c1 = W1[(2 * IN_F + 1) * HID + lane];
  const float w1c2 = W1[(2 * IN_F + 2) * HID + lane];

  const int gwave = __builtin_amdgcn_readfirstlane((blockIdx.x << 2) | wave);
  const int nw = gridDim.x << 2;

  for (int d = gwave; d < N; d += nw) {
    rowS[wave][lane] = ORD_NEG_INF;
    int m = cnt[d];                       // wave-uniform scalar load
    if (m > BCAP) m = BCAP;

    if (m > 0) {
      const float pvl = P[(size_t)d * HID + lane];  // lane = channel
      float maxv[4][4];
#pragma unroll
      for (int t = 0; t < 4; ++t)
#pragma unroll
        for (int r = 0; r < 4; ++r) maxv[t][r] = -INFINITY;

      const int ntile = (m + 15) >> 4;
      for (int tb = 0; tb < ntile; ++tb) {
        // ---- layer 1 for 16 edges (padding clamps to last valid: same dst, harmless for max) ----
#pragma unroll
        for (int i = 0; i < 16; ++i) {
          int idx = tb * 16 + i;
          if (idx > m - 1) idx = m - 1;
          float4 r = rec[(size_t)d * BCAP + idx];   // wave-uniform -> scalar load
          int s = __float_as_int(r.x);
          float pre = pvl + Q[(size_t)s * HID + lane];
          pre = fmaf(r.y, w1c0, pre);
          pre = fmaf(r.z, w1c1, pre);
          pre = fmaf(r.w, w1c2, pre);
          hB[wave][i][lane] = (_Float16)fmaxf(pre, 0.f);
        }
        __builtin_amdgcn_wave_barrier();

        // ---- layer 2: 8x mfma, B-frag hB[edge=eidx][k] ----
        const v8h bf0 = *(const v8h*)&hB[wave][eidx][quad * 8];
        const v8h bf1 = *(const v8h*)&hB[wave][eidx][32 + quad * 8];
#pragma unroll
        for (int t = 0; t < 4; ++t) {
          v4f acc = (v4f){0.f, 0.f, 0.f, 0.f};
          acc = __builtin_amdgcn_mfma_f32_16x16x32_f16(a_frag[t][0], bf0, acc, 0, 0, 0);
          acc = __builtin_amdgcn_mfma_f32_16x16x32_f16(a_frag[t][1], bf1, acc, 0, 0, 0);
#pragma unroll
          for (int r = 0; r < 4; ++r) maxv[t][r] = fmaxf(maxv[t][r], acc[r]);
        }
        __builtin_amdgcn_wave_barrier();
      }

      // ---- cross-edge-column (eidx) reduction via LDS atomic max ----
#pragma unroll
      for (int t = 0; t < 4; ++t)
#pragma unroll
        for (int r = 0; r < 4; ++r)
          atomicMax(&rowS[wave][t * 16 + quad * 4 + r], ordenc(maxv[t][r]));
    }
    __builtin_amdgcn_wave_barrier();

    // ---- one coalesced row store per dst (also covers empty: ORD_NEG_INF) ----
    agg[(size_t)d * HID + lane] = rowS[wave][lane];
    __builtin_amdgcn_wave_barrier();
  }
}

// Fallback for bucket-overflow edges (expected count: 0). One wave per edge,
// scalar layer2, atomicMax into agg. Runs after bucket_kernel (stream order).
__global__ __launch_bounds__(256) void overflow_kernel(
    const int* __restrict__ ei, const float* __restrict__ ea,
    const float* __restrict__ W1, const float* __restrict__ W2,
    const float* __restrict__ P, const float* __restrict__ Q,
    const int* __restrict__ ovf, const int* __restrict__ ovf_cnt,
    unsigned* __restrict__ agg, int E)
{
  __shared__ float hsh[4][HID];
  const int wave = threadIdx.x >> 6;
  const int lane = threadIdx.x & 63;

  int M = *ovf_cnt;
  if (M > OVF_CAP) M = OVF_CAP;
  if (M == 0) return;

  float w2r[HID];
#pragma unroll
  for (int j = 0; j < HID; ++j) w2r[j] = W2[j * HID + lane];
  const float w1c0 = W1[(2 * IN_F + 0) * HID + lane];
  const float w1c1 = W1[(2 * IN_F + 1) * HID + lane];
  const float w1c2 = W1[(2 * IN_F + 2) * HID + lane];

  const int gwave = __builtin_amdgcn_readfirstlane((blockIdx.x << 2) | wave);
  const int nw = gridDim.x << 2;
  for (int k = gwave; k < M; k += nw) {
    int e = ovf[k];
    int s = ei[e];
    int d = ei[(size_t)E + e];
    float pre = P[(size_t)d * HID + lane] + Q[(size_t)s * HID + lane];
    pre = fmaf(ea[e * 3 + 0], w1c0, pre);
    pre = fmaf(ea[e * 3 + 1], w1c1, pre);
    pre = fmaf(ea[e * 3 + 2], w1c2, pre);
    hsh[wave][lane] = fmaxf(pre, 0.f);
    __builtin_amdgcn_wave_barrier();
    float mv = 0.f;
#pragma unroll
    for (int j = 0; j < HID; ++j) mv = fmaf(hsh[wave][j], w2r[j], mv);
    atomicMax(&agg[(size_t)d * HID + lane], ordenc(mv));
    __builtin_amdgcn_wave_barrier();
  }
}

// 16 nodes per block: decode agg (empty -> 0, else +b2), out = sigmoid(agg @ Wo + bo)
__global__ __launch_bounds__(256) void out_kernel(
    const unsigned* __restrict__ agg,
    const float* __restrict__ b2,
    const float* __restrict__ Wo, const float* __restrict__ bo,
    float* __restrict__ out, int N)
{
  __shared__ float Wos[HID * OUTF];
  __shared__ float bos[OUTF];
  __shared__ float b2s[HID];
  __shared__ float aggs[16][HID + 1];

  for (int i = threadIdx.x; i < HID * OUTF; i += 256) Wos[i] = Wo[i];
  if (threadIdx.x < OUTF) bos[threadIdx.x] = bo[threadIdx.x];
  if (threadIdx.x < HID) b2s[threadIdx.x] = b2[threadIdx.x];
  __syncthreads();

  const int nodeBase = blockIdx.x * 16;
  {
    int ln = threadIdx.x >> 4;
    int k0 = (threadIdx.x & 15) * 4;
    int n = nodeBase + ln;
    if (n < N) {
      const uint4 u = *(const uint4*)&agg[n * HID + k0];
      aggs[ln][k0 + 0] = (u.x == ORD_NEG_INF) ? 0.f : orddec(u.x) + b2s[k0 + 0];
      aggs[ln][k0 + 1] = (u.y == ORD_NEG_INF) ? 0.f : orddec(u.y) + b2s[k0 + 1];
      aggs[ln][k0 + 2] = (u.z == ORD_NEG_INF) ? 0.f : orddec(u.z) + b2s[k0 + 2];
      aggs[ln][k0 + 3] = (u.w == ORD_NEG_INF) ? 0.f : orddec(u.w) + b2s[k0 + 3];
    }
  }
  __syncthreads();
  {
    int ln = threadIdx.x >> 4;
    int o = threadIdx.x & 15;
    int n = nodeBase + ln;
    if (n < N) {
      float acc = bos[o];
#pragma unroll
      for (int k = 0; k < HID; ++k) acc = fmaf(aggs[ln][k], Wos[k * OUTF + o], acc);
      out[n * OUTF + o] = 1.f / (1.f + __expf(-acc));
    }
  }
}

extern "C" void kernel_launch(void* const* d_in, const int* in_sizes, int n_in,
                              void* d_out, int out_size, void* d_ws, size_t ws_size,
                              hipStream_t stream) {
  const float* x  = (const float*)d_in[0];
  const int*   ei = (const int*)d_in[1];
  const float* ea = (const float*)d_in[2];
  const float* W1 = (const float*)d_in[3];
  const float* b1 = (const float*)d_in[4];
  const float* W2 = (const float*)d_in[5];
  const float* b2 = (const float*)d_in[6];
  const float* Wo = (const float*)d_in[7];
  const float* bo = (const float*)d_in[8];
  float* out = (float*)d_out;

  const int N = in_sizes[0] / IN_F;   // 50000
  const int E = in_sizes[1] / 2;      // 1600000

  // workspace layout (16B-aligned blocks):
  //   P [N*64 f32] | Q [N*64 f32] | agg [N*64 u32] | rec [N*BCAP float4]
  //   | cnt [N i32] | ovf_cnt [1 i32] | ovf [OVF_CAP i32]
  char* w = (char*)d_ws;
  float*    Pp  = (float*)w;                     w += (size_t)N * HID * 4;
  float*    Qp  = (float*)w;                     w += (size_t)N * HID * 4;
  unsigned* agg = (unsigned*)w;                  w += (size_t)N * HID * 4;
  float4*   rec = (float4*)w;                    w += (size_t)N * BCAP * 16;
  int*      cnt = (int*)w;                       w += (size_t)N * 4;
  int*  ovf_cnt = (int*)w;                       w += 16;   // keep alignment
  int*      ovf = (int*)w;

  // zero bucket counters + overflow counter (one contiguous region)
  hipMemsetAsync(cnt, 0, (size_t)N * 4 + 16, stream);

  node_pre_kernel<<<512, 256, 0, stream>>>(x, W1, b1, Pp, Qp, N);
  scatter_kernel<<<(E + 255) / 256, 256, 0, stream>>>(ei, ea, rec, cnt, ovf, ovf_cnt, E);
  bucket_kernel<<<2048, 256, 0, stream>>>(rec, cnt, W1, W2, Pp, Qp, agg, N);
  overflow_kernel<<<256, 256, 0, stream>>>(ei, ea, W1, W2, Pp, Qp, ovf, ovf_cnt, agg, E);
  out_kernel<<<(N + 15) / 16, 256, 0, stream>>>(agg, b2, Wo, bo, out, N);
}

// Round 8
// 296.204 us; speedup vs baseline: 1.7272x; 1.1275x over previous
//
#include <hip/hip_runtime.h>

#define IN_F 32
#define HID 64
#define OUTF 16
#define NSUB 8                     // sub-buckets per dst (XCD-locality heuristic)
#define SB_CAP 16                  // records per sub-bucket
#define OVF_CAP 65536
#define ORD_NEG_INF 0x007FFFFFu    // ordenc(-inf)

typedef _Float16 v8h __attribute__((ext_vector_type(8)));
typedef float v4f __attribute__((ext_vector_type(4)));

__device__ __forceinline__ unsigned ordenc(float v) {
  unsigned b = __float_as_uint(v);
  return (b & 0x80000000u) ? ~b : (b | 0x80000000u);
}
__device__ __forceinline__ float orddec(unsigned u) {
  unsigned b = (u & 0x80000000u) ? (u & 0x7FFFFFFFu) : ~u;
  return __uint_as_float(b);
}
__device__ __forceinline__ unsigned short f2h_bits(float f) {
  _Float16 h = (_Float16)f; unsigned short u; __builtin_memcpy(&u, &h, 2); return u;
}
__device__ __forceinline__ float h_bits2f(unsigned short u) {
  _Float16 h; __builtin_memcpy(&h, &u, 2); return (float)h;
}

// Per-node precompute: P[n] = x[n] @ (W1A - W1B) + b1,  Q[n] = x[n] @ W1B
__global__ __launch_bounds__(256) void node_pre_kernel(
    const float* __restrict__ x, const float* __restrict__ W1,
    const float* __restrict__ b1, float* __restrict__ P, float* __restrict__ Q, int N)
{
  const int lane = threadIdx.x & 63;
  float w1d[IN_F], w1b[IN_F];
#pragma unroll
  for (int c = 0; c < IN_F; ++c) {
    w1b[c] = W1[(IN_F + c) * HID + lane];
    w1d[c] = W1[c * HID + lane] - w1b[c];
  }
  const float b1v = b1[lane];
  int gw = __builtin_amdgcn_readfirstlane((blockIdx.x << 2) | (threadIdx.x >> 6));
  const int nwaves = gridDim.x << 2;
  for (int n = gw; n < N; n += nwaves) {
    float p = b1v, q = 0.f;
#pragma unroll
    for (int c = 0; c < IN_F; ++c) {
      float xv = x[n * IN_F + c];
      p = fmaf(xv, w1d[c], p);
      q = fmaf(xv, w1b[c], q);
    }
    P[n * HID + lane] = p;
    Q[n * HID + lane] = q;
  }
}

// Scatter edges into per-(dst, XCD-group) sub-buckets; 8B packed records.
__global__ __launch_bounds__(256) void scatter_kernel(
    const int* __restrict__ ei, const float* __restrict__ ea,
    uint2* __restrict__ rec, int* __restrict__ cnt,
    int* __restrict__ ovf, int* __restrict__ ovf_cnt, int E)
{
  int e = blockIdx.x * 256 + threadIdx.x;
  if (e >= E) return;
  int s = ei[e];
  int d = ei[(size_t)E + e];
  float a0 = ea[e * 3 + 0], a1 = ea[e * 3 + 1], a2 = ea[e * 3 + 2];
  int g = blockIdx.x & (NSUB - 1);     // ~XCD id (perf heuristic only)
  int sb = d * NSUB + g;
  int pos = atomicAdd(&cnt[sb], 1);
  if (pos < SB_CAP) {
    uint2 r;
    r.x = (unsigned)s | ((unsigned)f2h_bits(a0) << 16);   // src < 65536
    r.y = (unsigned)f2h_bits(a1) | ((unsigned)f2h_bits(a2) << 16);
    rec[(size_t)sb * SB_CAP + pos] = r;
  } else {
    int oi = atomicAdd(ovf_cnt, 1);
    if (oi < OVF_CAP) ovf[oi] = e;
  }
}

// One wave per dst: stage all sub-bucket records to LDS, 16-edge MFMA tiles
// with Q-gather prefetch, butterfly max reduction (no LDS atomics), one
// coalesced row store. Zero global atomics.
__global__ __launch_bounds__(256) void bucket_kernel(
    const uint2* __restrict__ rec, const int* __restrict__ cnt,
    const float* __restrict__ W1, const float* __restrict__ W2,
    const float* __restrict__ P, const float* __restrict__ Q,
    unsigned* __restrict__ agg, int N)
{
  __shared__ __align__(16) _Float16 hB[4][16][72];   // [wave][edge][ch]
  __shared__ uint2 stage[4][NSUB * SB_CAP];          // [wave][record]
  __shared__ unsigned rowS[4][HID];

  const int wave = threadIdx.x >> 6;
  const int lane = threadIdx.x & 63;
  const int quad = lane >> 4;
  const int eidx = lane & 15;

  // A-operand: W2^T fragments, fp16, loop-invariant (verified R5/R7).
  v8h a_frag[4][2];
#pragma unroll
  for (int t = 0; t < 4; ++t)
#pragma unroll
    for (int ks = 0; ks < 2; ++ks)
#pragma unroll
      for (int j = 0; j < 8; ++j)
        a_frag[t][ks][j] = (_Float16)W2[(ks * 32 + quad * 8 + j) * HID + t * 16 + eidx];

  const float w1c0 = W1[(2 * IN_F + 0) * HID + lane];
  const float w1c1 = W1[(2 * IN_F + 1) * HID + lane];
  const float w1c2 = W1[(2 * IN_F + 2) * HID + lane];

  const int gwave = __builtin_amdgcn_readfirstlane((blockIdx.x << 2) | wave);
  const int nw = gridDim.x << 2;

  for (int d = gwave; d < N; d += nw) {
    // ---- sub-bucket counts (wave-uniform) + prefix ----
    const uint4 ca = *(const uint4*)&cnt[(size_t)d * NSUB];
    const uint4 cb = *(const uint4*)&cnt[(size_t)d * NSUB + 4];
    int c0 = min((int)ca.x, SB_CAP), c1 = min((int)ca.y, SB_CAP);
    int c2 = min((int)ca.z, SB_CAP), c3 = min((int)ca.w, SB_CAP);
    int c4 = min((int)cb.x, SB_CAP), c5 = min((int)cb.y, SB_CAP);
    int c6 = min((int)cb.z, SB_CAP), c7 = min((int)cb.w, SB_CAP);
    int p1 = c0, p2 = p1 + c1, p3 = p2 + c2, p4 = p3 + c3;
    int p5 = p4 + c4, p6 = p5 + c5, p7 = p6 + c6;
    const int m = p7 + c7;

    if (m == 0) { agg[(size_t)d * HID + lane] = ORD_NEG_INF; continue; }

    // ---- stage records into LDS (lane i handles concat position i) ----
#pragma unroll
    for (int rr = 0; rr < 2; ++rr) {
      int i = rr * 64 + lane;
      if (i < m) {
        int g = 0, base = 0;
        if (i >= p1) { g = 1; base = p1; }
        if (i >= p2) { g = 2; base = p2; }
        if (i >= p3) { g = 3; base = p3; }
        if (i >= p4) { g = 4; base = p4; }
        if (i >= p5) { g = 5; base = p5; }
        if (i >= p6) { g = 6; base = p6; }
        if (i >= p7) { g = 7; base = p7; }
        stage[wave][i] = rec[((size_t)d * NSUB + g) * SB_CAP + (i - base)];
      }
    }
    __builtin_amdgcn_wave_barrier();   // wave-internal DS in-order

    const float pvl = P[(size_t)d * HID + lane];
    float maxv[4][4];
#pragma unroll
    for (int t = 0; t < 4; ++t)
#pragma unroll
      for (int r = 0; r < 4; ++r) maxv[t][r] = -INFINITY;

    const int ntile = (m + 15) >> 4;
    float qv[16];
#pragma unroll
    for (int i = 0; i < 16; ++i) {
      int idx = min(i, m - 1);
      uint2 r = stage[wave][idx];
      qv[i] = Q[(size_t)(r.x & 0xFFFFu) * HID + lane];
    }

    for (int tb = 0; tb < ntile; ++tb) {
      // ---- layer 1 for this tile (padding clamps to last record: idempotent for max) ----
#pragma unroll
      for (int i = 0; i < 16; ++i) {
        int idx = min(tb * 16 + i, m - 1);
        uint2 r = stage[wave][idx];             // LDS broadcast
        float pre = pvl + qv[i];
        pre = fmaf(h_bits2f((unsigned short)(r.x >> 16)), w1c0, pre);
        pre = fmaf(h_bits2f((unsigned short)(r.y & 0xFFFFu)), w1c1, pre);
        pre = fmaf(h_bits2f((unsigned short)(r.y >> 16)), w1c2, pre);
        hB[wave][i][lane] = (_Float16)fmaxf(pre, 0.f);
      }
      // ---- prefetch next tile's Q gathers (hidden under MFMA) ----
      if (tb + 1 < ntile) {
#pragma unroll
        for (int i = 0; i < 16; ++i) {
          int idx = min((tb + 1) * 16 + i, m - 1);
          uint2 r = stage[wave][idx];
          qv[i] = Q[(size_t)(r.x & 0xFFFFu) * HID + lane];
        }
      }
      __builtin_amdgcn_wave_barrier();

      const v8h bf0 = *(const v8h*)&hB[wave][eidx][quad * 8];
      const v8h bf1 = *(const v8h*)&hB[wave][eidx][32 + quad * 8];
#pragma unroll
      for (int t = 0; t < 4; ++t) {
        v4f acc = (v4f){0.f, 0.f, 0.f, 0.f};
        acc = __builtin_amdgcn_mfma_f32_16x16x32_f16(a_frag[t][0], bf0, acc, 0, 0, 0);
        acc = __builtin_amdgcn_mfma_f32_16x16x32_f16(a_frag[t][1], bf1, acc, 0, 0, 0);
#pragma unroll
        for (int r = 0; r < 4; ++r) maxv[t][r] = fmaxf(maxv[t][r], acc[r]);
      }
      __builtin_amdgcn_wave_barrier();
    }

    // ---- butterfly max over the 16 edge-columns (eidx) — registers only ----
#pragma unroll
    for (int t = 0; t < 4; ++t)
#pragma unroll
      for (int r = 0; r < 4; ++r) {
        float v = maxv[t][r];
        v = fmaxf(v, __shfl_xor(v, 1, 64));
        v = fmaxf(v, __shfl_xor(v, 2, 64));
        v = fmaxf(v, __shfl_xor(v, 4, 64));
        v = fmaxf(v, __shfl_xor(v, 8, 64));
        maxv[t][r] = v;
      }
    // lane (quad, eidx) is the unique writer for channel (eidx>>2)*16 + quad*4 + (eidx&3)
    float val = maxv[0][0];
#pragma unroll
    for (int t = 0; t < 4; ++t)
#pragma unroll
      for (int r = 0; r < 4; ++r)
        val = (eidx == t * 4 + r) ? maxv[t][r] : val;
    rowS[wave][((eidx >> 2) << 4) + (quad << 2) + (eidx & 3)] = ordenc(val);
    __builtin_amdgcn_wave_barrier();
    agg[(size_t)d * HID + lane] = rowS[wave][lane];
    __builtin_amdgcn_wave_barrier();
  }
}

// Fallback for sub-bucket overflow (expected ~0 edges). fp32-exact path.
__global__ __launch_bounds__(256) void overflow_kernel(
    const int* __restrict__ ei, const float* __restrict__ ea,
    const float* __restrict__ W1, const float* __restrict__ W2,
    const float* __restrict__ P, const float* __restrict__ Q,
    const int* __restrict__ ovf, const int* __restrict__ ovf_cnt,
    unsigned* __restrict__ agg, int E)
{
  __shared__ float hsh[4][HID];
  const int wave = threadIdx.x >> 6;
  const int lane = threadIdx.x & 63;

  int M = *ovf_cnt;
  if (M > OVF_CAP) M = OVF_CAP;
  if (M == 0) return;

  float w2r[HID];
#pragma unroll
  for (int j = 0; j < HID; ++j) w2r[j] = W2[j * HID + lane];
  const float w1c0 = W1[(2 * IN_F + 0) * HID + lane];
  const float w1c1 = W1[(2 * IN_F + 1) * HID + lane];
  const float w1c2 = W1[(2 * IN_F + 2) * HID + lane];

  const int gwave = __builtin_amdgcn_readfirstlane((blockIdx.x << 2) | wave);
  const int nw = gridDim.x << 2;
  for (int k = gwave; k < M; k += nw) {
    int e = ovf[k];
    int s = ei[e];
    int d = ei[(size_t)E + e];
    float pre = P[(size_t)d * HID + lane] + Q[(size_t)s * HID + lane];
    pre = fmaf(ea[e * 3 + 0], w1c0, pre);
    pre = fmaf(ea[e * 3 + 1], w1c1, pre);
    pre = fmaf(ea[e * 3 + 2], w1c2, pre);
    hsh[wave][lane] = fmaxf(pre, 0.f);
    __builtin_amdgcn_wave_barrier();
    float mv = 0.f;
#pragma unroll
    for (int j = 0; j < HID; ++j) mv = fmaf(hsh[wave][j], w2r[j], mv);
    atomicMax(&agg[(size_t)d * HID + lane], ordenc(mv));
    __builtin_amdgcn_wave_barrier();
  }
}

// 16 nodes per block: decode agg (empty -> 0, else +b2), out = sigmoid(agg @ Wo + bo)
__global__ __launch_bounds__(256) void out_kernel(
    const unsigned* __restrict__ agg,
    const float* __restrict__ b2,
    const float* __restrict__ Wo, const float* __restrict__ bo,
    float* __restrict__ out, int N)
{
  __shared__ float Wos[HID * OUTF];
  __shared__ float bos[OUTF];
  __shared__ float b2s[HID];
  __shared__ float aggs[16][HID + 1];

  for (int i = threadIdx.x; i < HID * OUTF; i += 256) Wos[i] = Wo[i];
  if (threadIdx.x < OUTF) bos[threadIdx.x] = bo[threadIdx.x];
  if (threadIdx.x < HID) b2s[threadIdx.x] = b2[threadIdx.x];
  __syncthreads();

  const int nodeBase = blockIdx.x * 16;
  {
    int ln = threadIdx.x >> 4;
    int k0 = (threadIdx.x & 15) * 4;
    int n = nodeBase + ln;
    if (n < N) {
      const uint4 u = *(const uint4*)&agg[n * HID + k0];
      aggs[ln][k0 + 0] = (u.x == ORD_NEG_INF) ? 0.f : orddec(u.x) + b2s[k0 + 0];
      aggs[ln][k0 + 1] = (u.y == ORD_NEG_INF) ? 0.f : orddec(u.y) + b2s[k0 + 1];
      aggs[ln][k0 + 2] = (u.z == ORD_NEG_INF) ? 0.f : orddec(u.z) + b2s[k0 + 2];
      aggs[ln][k0 + 3] = (u.w == ORD_NEG_INF) ? 0.f : orddec(u.w) + b2s[k0 + 3];
    }
  }
  __syncthreads();
  {
    int ln = threadIdx.x >> 4;
    int o = threadIdx.x & 15;
    int n = nodeBase + ln;
    if (n < N) {
      float acc = bos[o];
#pragma unroll
      for (int k = 0; k < HID; ++k) acc = fmaf(aggs[ln][k], Wos[k * OUTF + o], acc);
      out[n * OUTF + o] = 1.f / (1.f + __expf(-acc));
    }
  }
}

extern "C" void kernel_launch(void* const* d_in, const int* in_sizes, int n_in,
                              void* d_out, int out_size, void* d_ws, size_t ws_size,
                              hipStream_t stream) {
  const float* x  = (const float*)d_in[0];
  const int*   ei = (const int*)d_in[1];
  const float* ea = (const float*)d_in[2];
  const float* W1 = (const float*)d_in[3];
  const float* b1 = (const float*)d_in[4];
  const float* W2 = (const float*)d_in[5];
  const float* b2 = (const float*)d_in[6];
  const float* Wo = (const float*)d_in[7];
  const float* bo = (const float*)d_in[8];
  float* out = (float*)d_out;

  const int N = in_sizes[0] / IN_F;   // 50000
  const int E = in_sizes[1] / 2;      // 1600000

  // ws layout: P | Q | agg | rec (N*8*16 uint2 = 51.2MB) | cnt (N*8 i32) | ovf_cnt | ovf
  char* w = (char*)d_ws;
  float*    Pp  = (float*)w;                     w += (size_t)N * HID * 4;
  float*    Qp  = (float*)w;                     w += (size_t)N * HID * 4;
  unsigned* agg = (unsigned*)w;                  w += (size_t)N * HID * 4;
  uint2*    rec = (uint2*)w;                     w += (size_t)N * NSUB * SB_CAP * 8;
  int*      cnt = (int*)w;                       w += (size_t)N * NSUB * 4;
  int*  ovf_cnt = (int*)w;                       w += 16;
  int*      ovf = (int*)w;

  hipMemsetAsync(cnt, 0, (size_t)N * NSUB * 4 + 16, stream);

  node_pre_kernel<<<512, 256, 0, stream>>>(x, W1, b1, Pp, Qp, N);
  scatter_kernel<<<(E + 255) / 256, 256, 0, stream>>>(ei, ea, rec, cnt, ovf, ovf_cnt, E);
  bucket_kernel<<<2048, 256, 0, stream>>>(rec, cnt, W1, W2, Pp, Qp, agg, N);
  overflow_kernel<<<256, 256, 0, stream>>>(ei, ea, W1, W2, Pp, Qp, ovf, ovf_cnt, agg, E);
  out_kernel<<<(N + 15) / 16, 256, 0, stream>>>(agg, b2, Wo, bo, out, N);
}

// Round 9
// 292.414 us; speedup vs baseline: 1.7496x; 1.0130x over previous
//
#include <hip/hip_runtime.h>

#define IN_F 32
#define HID 64
#define OUTF 16
#define NSUB 8                     // sub-buckets per dst (XCD-locality heuristic)
#define SB_CAP 16                  // records per sub-bucket
#define OVF_CAP 65536
#define ORD_NEG_INF 0x007FFFFFu    // ordenc(-inf)

typedef _Float16 v8h __attribute__((ext_vector_type(8)));
typedef float v4f __attribute__((ext_vector_type(4)));

__device__ __forceinline__ unsigned ordenc(float v) {
  unsigned b = __float_as_uint(v);
  return (b & 0x80000000u) ? ~b : (b | 0x80000000u);
}
__device__ __forceinline__ float orddec(unsigned u) {
  unsigned b = (u & 0x80000000u) ? (u & 0x7FFFFFFFu) : ~u;
  return __uint_as_float(b);
}
__device__ __forceinline__ unsigned short f2h_bits(float f) {
  _Float16 h = (_Float16)f; unsigned short u; __builtin_memcpy(&u, &h, 2); return u;
}
__device__ __forceinline__ float h_bits2f(unsigned short u) {
  _Float16 h; __builtin_memcpy(&h, &u, 2); return (float)h;
}

// Fused: scatter (blocks [0, nSB)) + node_pre (blocks [nSB, nSB+512)).
// Scatter: 4 edges/thread, all atomics issued before ea loads (MLP).
__global__ __launch_bounds__(256) void pre_scatter_kernel(
    const float* __restrict__ x, const int* __restrict__ ei,
    const float* __restrict__ ea, const float* __restrict__ W1,
    const float* __restrict__ b1,
    float* __restrict__ P, float* __restrict__ Q,
    uint2* __restrict__ rec, int* __restrict__ cnt,
    int* __restrict__ ovf, int* __restrict__ ovf_cnt,
    int E, int N, int nSB)
{
  if (blockIdx.x < (unsigned)nSB) {
    // ---------------- scatter ----------------
    const int t = threadIdx.x;
    const int base = blockIdx.x * 1024;
    const int g = blockIdx.x & (NSUB - 1);   // ~XCD id (perf heuristic only)
    int e[4], s[4], d[4], pos[4];
    bool v[4];
#pragma unroll
    for (int i = 0; i < 4; ++i) {
      e[i] = base + i * 256 + t;
      v[i] = e[i] < E;
      int ec = v[i] ? e[i] : 0;
      s[i] = ei[ec];
      d[i] = ei[(size_t)E + ec];
    }
#pragma unroll
    for (int i = 0; i < 4; ++i)
      pos[i] = v[i] ? atomicAdd(&cnt[d[i] * NSUB + g], 1) : SB_CAP;
    float a0[4], a1[4], a2[4];
#pragma unroll
    for (int i = 0; i < 4; ++i) {
      int ec = v[i] ? e[i] : 0;
      a0[i] = ea[ec * 3 + 0]; a1[i] = ea[ec * 3 + 1]; a2[i] = ea[ec * 3 + 2];
    }
#pragma unroll
    for (int i = 0; i < 4; ++i) {
      if (!v[i]) continue;
      if (pos[i] < SB_CAP) {
        uint2 r;
        r.x = (unsigned)s[i] | ((unsigned)f2h_bits(a0[i]) << 16);  // src < 65536
        r.y = (unsigned)f2h_bits(a1[i]) | ((unsigned)f2h_bits(a2[i]) << 16);
        rec[((size_t)d[i] * NSUB + g) * SB_CAP + pos[i]] = r;
      } else {
        int oi = atomicAdd(ovf_cnt, 1);
        if (oi < OVF_CAP) ovf[oi] = e[i];
      }
    }
    return;
  }
  // ---------------- node_pre ----------------
  const int lane = threadIdx.x & 63;
  float w1d[IN_F], w1b[IN_F];
#pragma unroll
  for (int c = 0; c < IN_F; ++c) {
    w1b[c] = W1[(IN_F + c) * HID + lane];
    w1d[c] = W1[c * HID + lane] - w1b[c];
  }
  const float b1v = b1[lane];
  int gw = __builtin_amdgcn_readfirstlane((((int)blockIdx.x - nSB) << 2) | (threadIdx.x >> 6));
  const int nwaves = 512 << 2;
  for (int n = gw; n < N; n += nwaves) {
    float p = b1v, q = 0.f;
#pragma unroll
    for (int c = 0; c < IN_F; ++c) {
      float xv = x[n * IN_F + c];
      p = fmaf(xv, w1d[c], p);
      q = fmaf(xv, w1b[c], q);
    }
    P[n * HID + lane] = p;
    Q[n * HID + lane] = q;
  }
}

// One wave per dst, dst-level software pipeline (double-buffered LDS stage):
// while processing dst d, prefetch dst d+nw's counts -> records -> P row.
// Butterfly max reduction, direct permuted row store (no rowS round-trip).
__global__ __launch_bounds__(256) void bucket_kernel(
    const uint2* __restrict__ rec, const int* __restrict__ cnt,
    const float* __restrict__ W1, const float* __restrict__ W2,
    const float* __restrict__ P, const float* __restrict__ Q,
    unsigned* __restrict__ agg, int N)
{
  __shared__ __align__(16) _Float16 hB[4][16][72];     // [wave][edge][ch]
  __shared__ uint2 stage[4][2][NSUB * SB_CAP];         // [wave][buf][record] 8 KB

  const int wave = threadIdx.x >> 6;
  const int lane = threadIdx.x & 63;
  const int quad = lane >> 4;
  const int eidx = lane & 15;
  // channel this lane stores in the final permuted row write
  const int mych = ((eidx >> 2) << 4) + (quad << 2) + (eidx & 3);

  // A-operand: W2^T fragments, fp16, loop-invariant (verified R5/R7/R8).
  v8h a_frag[4][2];
#pragma unroll
  for (int t = 0; t < 4; ++t)
#pragma unroll
    for (int ks = 0; ks < 2; ++ks)
#pragma unroll
      for (int j = 0; j < 8; ++j)
        a_frag[t][ks][j] = (_Float16)W2[(ks * 32 + quad * 8 + j) * HID + t * 16 + eidx];

  const float w1c0 = W1[(2 * IN_F + 0) * HID + lane];
  const float w1c1 = W1[(2 * IN_F + 1) * HID + lane];
  const float w1c2 = W1[(2 * IN_F + 2) * HID + lane];

  const int gwave = __builtin_amdgcn_readfirstlane((blockIdx.x << 2) | wave);
  const int nw = gridDim.x << 2;

  int d = gwave;
  if (d >= N) return;   // waves are independent (no cross-wave LDS / syncthreads)

  // ---- preload dst d: counts -> prefix -> record regs + P row ----
  int m; uint2 r0, r1; float pP;
  {
    const uint4 ca = *(const uint4*)&cnt[(size_t)d * NSUB];
    const uint4 cb = *(const uint4*)&cnt[(size_t)d * NSUB + 4];
    int c0 = min((int)ca.x, SB_CAP), c1 = min((int)ca.y, SB_CAP);
    int c2 = min((int)ca.z, SB_CAP), c3 = min((int)ca.w, SB_CAP);
    int c4 = min((int)cb.x, SB_CAP), c5 = min((int)cb.y, SB_CAP);
    int c6 = min((int)cb.z, SB_CAP), c7 = min((int)cb.w, SB_CAP);
    int p1 = c0, p2 = p1 + c1, p3 = p2 + c2, p4 = p3 + c3;
    int p5 = p4 + c4, p6 = p5 + c5, p7 = p6 + c6;
    m = p7 + c7;
#pragma unroll
    for (int rr = 0; rr < 2; ++rr) {
      int i = rr * 64 + lane;
      if (i < m) {
        int g = 0, base = 0;
        if (i >= p1) { g = 1; base = p1; }
        if (i >= p2) { g = 2; base = p2; }
        if (i >= p3) { g = 3; base = p3; }
        if (i >= p4) { g = 4; base = p4; }
        if (i >= p5) { g = 5; base = p5; }
        if (i >= p6) { g = 6; base = p6; }
        if (i >= p7) { g = 7; base = p7; }
        uint2 rv = rec[((size_t)d * NSUB + g) * SB_CAP + (i - base)];
        if (rr == 0) r0 = rv; else r1 = rv;
      }
    }
    pP = P[(size_t)d * HID + lane];
  }

  int cur = 0;
  while (d < N) {
    const int dn = d + nw;
    const int m_cur = m;
    const float pvl = pP;

    // ---- commit staged records for current dst to LDS buffer `cur` ----
    if (lane < m_cur) stage[wave][cur][lane] = r0;
    if (64 + lane < m_cur) stage[wave][cur][64 + lane] = r1;
    __builtin_amdgcn_wave_barrier();

    if (m_cur > 0) {
      // ---- tile-0 Q prefetch (issued BEFORE next-dst loads: vmcnt-friendly) ----
      float qv[16];
#pragma unroll
      for (int i = 0; i < 16; ++i) {
        int idx = min(i, m_cur - 1);
        uint2 rr = stage[wave][cur][idx];
        qv[i] = Q[(size_t)(rr.x & 0xFFFFu) * HID + lane];
      }

      // ---- prefetch next dst (counts -> records -> P), lands under MFMA work ----
      if (dn < N) {
        const uint4 ca = *(const uint4*)&cnt[(size_t)dn * NSUB];
        const uint4 cb = *(const uint4*)&cnt[(size_t)dn * NSUB + 4];
        int c0 = min((int)ca.x, SB_CAP), c1 = min((int)ca.y, SB_CAP);
        int c2 = min((int)ca.z, SB_CAP), c3 = min((int)ca.w, SB_CAP);
        int c4 = min((int)cb.x, SB_CAP), c5 = min((int)cb.y, SB_CAP);
        int c6 = min((int)cb.z, SB_CAP), c7 = min((int)cb.w, SB_CAP);
        int p1 = c0, p2 = p1 + c1, p3 = p2 + c2, p4 = p3 + c3;
        int p5 = p4 + c4, p6 = p5 + c5, p7 = p6 + c6;
        m = p7 + c7;
#pragma unroll
        for (int rr = 0; rr < 2; ++rr) {
          int i = rr * 64 + lane;
          if (i < m) {
            int g = 0, base = 0;
            if (i >= p1) { g = 1; base = p1; }
            if (i >= p2) { g = 2; base = p2; }
            if (i >= p3) { g = 3; base = p3; }
            if (i >= p4) { g = 4; base = p4; }
            if (i >= p5) { g = 5; base = p5; }
            if (i >= p6) { g = 6; base = p6; }
            if (i >= p7) { g = 7; base = p7; }
            uint2 rv = rec[((size_t)dn * NSUB + g) * SB_CAP + (i - base)];
            if (rr == 0) r0 = rv; else r1 = rv;
          }
        }
        pP = P[(size_t)dn * HID + lane];
      }

      // ---- process current dst: 16-edge MFMA tiles ----
      float maxv[4][4];
#pragma unroll
      for (int t = 0; t < 4; ++t)
#pragma unroll
        for (int r = 0; r < 4; ++r) maxv[t][r] = -INFINITY;

      const int ntile = (m_cur + 15) >> 4;
      for (int tb = 0; tb < ntile; ++tb) {
#pragma unroll
        for (int i = 0; i < 16; ++i) {
          int idx = min(tb * 16 + i, m_cur - 1);
          uint2 rr = stage[wave][cur][idx];       // LDS broadcast
          float pre = pvl + qv[i];
          pre = fmaf(h_bits2f((unsigned short)(rr.x >> 16)), w1c0, pre);
          pre = fmaf(h_bits2f((unsigned short)(rr.y & 0xFFFFu)), w1c1, pre);
          pre = fmaf(h_bits2f((unsigned short)(rr.y >> 16)), w1c2, pre);
          hB[wave][i][lane] = (_Float16)fmaxf(pre, 0.f);
        }
        if (tb + 1 < ntile) {
#pragma unroll
          for (int i = 0; i < 16; ++i) {
            int idx = min((tb + 1) * 16 + i, m_cur - 1);
            uint2 rr = stage[wave][cur][idx];
            qv[i] = Q[(size_t)(rr.x & 0xFFFFu) * HID + lane];
          }
        }
        __builtin_amdgcn_wave_barrier();

        const v8h bf0 = *(const v8h*)&hB[wave][eidx][quad * 8];
        const v8h bf1 = *(const v8h*)&hB[wave][eidx][32 + quad * 8];
#pragma unroll
        for (int t = 0; t < 4; ++t) {
          v4f acc = (v4f){0.f, 0.f, 0.f, 0.f};
          acc = __builtin_amdgcn_mfma_f32_16x16x32_f16(a_frag[t][0], bf0, acc, 0, 0, 0);
          acc = __builtin_amdgcn_mfma_f32_16x16x32_f16(a_frag[t][1], bf1, acc, 0, 0, 0);
#pragma unroll
          for (int r = 0; r < 4; ++r) maxv[t][r] = fmaxf(maxv[t][r], acc[r]);
        }
        __builtin_amdgcn_wave_barrier();
      }

      // ---- butterfly max over the 16 edge-columns, direct permuted row store ----
#pragma unroll
      for (int t = 0; t < 4; ++t)
#pragma unroll
        for (int r = 0; r < 4; ++r) {
          float v = maxv[t][r];
          v = fmaxf(v, __shfl_xor(v, 1, 64));
          v = fmaxf(v, __shfl_xor(v, 2, 64));
          v = fmaxf(v, __shfl_xor(v, 4, 64));
          v = fmaxf(v, __shfl_xor(v, 8, 64));
          maxv[t][r] = v;
        }
      float val = maxv[0][0];
#pragma unroll
      for (int t = 0; t < 4; ++t)
#pragma unroll
        for (int r = 0; r < 4; ++r)
          val = (eidx == t * 4 + r) ? maxv[t][r] : val;
      agg[(size_t)d * HID + mych] = ordenc(val);   // permutation within one 256B row
    } else {
      // empty dst; still run the next-dst prefetch to keep the pipeline primed
      if (dn < N) {
        const uint4 ca = *(const uint4*)&cnt[(size_t)dn * NSUB];
        const uint4 cb = *(const uint4*)&cnt[(size_t)dn * NSUB + 4];
        int c0 = min((int)ca.x, SB_CAP), c1 = min((int)ca.y, SB_CAP);
        int c2 = min((int)ca.z, SB_CAP), c3 = min((int)ca.w, SB_CAP);
        int c4 = min((int)cb.x, SB_CAP), c5 = min((int)cb.y, SB_CAP);
        int c6 = min((int)cb.z, SB_CAP), c7 = min((int)cb.w, SB_CAP);
        int p1 = c0, p2 = p1 + c1, p3 = p2 + c2, p4 = p3 + c3;
        int p5 = p4 + c4, p6 = p5 + c5, p7 = p6 + c6;
        m = p7 + c7;
#pragma unroll
        for (int rr = 0; rr < 2; ++rr) {
          int i = rr * 64 + lane;
          if (i < m) {
            int g = 0, base = 0;
            if (i >= p1) { g = 1; base = p1; }
            if (i >= p2) { g = 2; base = p2; }
            if (i >= p3) { g = 3; base = p3; }
            if (i >= p4) { g = 4; base = p4; }
            if (i >= p5) { g = 5; base = p5; }
            if (i >= p6) { g = 6; base = p6; }
            if (i >= p7) { g = 7; base = p7; }
            uint2 rv = rec[((size_t)dn * NSUB + g) * SB_CAP + (i - base)];
            if (rr == 0) r0 = rv; else r1 = rv;
          }
        }
        pP = P[(size_t)dn * HID + lane];
      }
      agg[(size_t)d * HID + lane] = ORD_NEG_INF;
    }
    d = dn; cur ^= 1;
  }
}

// Fallback for sub-bucket overflow (expected ~0 edges). fp32-exact path.
__global__ __launch_bounds__(256) void overflow_kernel(
    const int* __restrict__ ei, const float* __restrict__ ea,
    const float* __restrict__ W1, const float* __restrict__ W2,
    const float* __restrict__ P, const float* __restrict__ Q,
    const int* __restrict__ ovf, const int* __restrict__ ovf_cnt,
    unsigned* __restrict__ agg, int E)
{
  __shared__ float hsh[4][HID];
  const int wave = threadIdx.x >> 6;
  const int lane = threadIdx.x & 63;

  int M = *ovf_cnt;
  if (M > OVF_CAP) M = OVF_CAP;
  if (M == 0) return;

  float w2r[HID];
#pragma unroll
  for (int j = 0; j < HID; ++j) w2r[j] = W2[j * HID + lane];
  const float w1c0 = W1[(2 * IN_F + 0) * HID + lane];
  const float w1c1 = W1[(2 * IN_F + 1) * HID + lane];
  const float w1c2 = W1[(2 * IN_F + 2) * HID + lane];

  const int gwave = __builtin_amdgcn_readfirstlane((blockIdx.x << 2) | wave);
  const int nw = gridDim.x << 2;
  for (int k = gwave; k < M; k += nw) {
    int e = ovf[k];
    int s = ei[e];
    int d = ei[(size_t)E + e];
    float pre = P[(size_t)d * HID + lane] + Q[(size_t)s * HID + lane];
    pre = fmaf(ea[e * 3 + 0], w1c0, pre);
    pre = fmaf(ea[e * 3 + 1], w1c1, pre);
    pre = fmaf(ea[e * 3 + 2], w1c2, pre);
    hsh[wave][lane] = fmaxf(pre, 0.f);
    __builtin_amdgcn_wave_barrier();
    float mv = 0.f;
#pragma unroll
    for (int j = 0; j < HID; ++j) mv = fmaf(hsh[wave][j], w2r[j], mv);
    atomicMax(&agg[(size_t)d * HID + lane], ordenc(mv));
    __builtin_amdgcn_wave_barrier();
  }
}

// 16 nodes per block: decode agg (empty -> 0, else +b2), out = sigmoid(agg @ Wo + bo)
__global__ __launch_bounds__(256) void out_kernel(
    const unsigned* __restrict__ agg,
    const float* __restrict__ b2,
    const float* __restrict__ Wo, const float* __restrict__ bo,
    float* __restrict__ out, int N)
{
  __shared__ float Wos[HID * OUTF];
  __shared__ float bos[OUTF];
  __shared__ float b2s[HID];
  __shared__ float aggs[16][HID + 1];

  for (int i = threadIdx.x; i < HID * OUTF; i += 256) Wos[i] = Wo[i];
  if (threadIdx.x < OUTF) bos[threadIdx.x] = bo[threadIdx.x];
  if (threadIdx.x < HID) b2s[threadIdx.x] = b2[threadIdx.x];
  __syncthreads();

  const int nodeBase = blockIdx.x * 16;
  {
    int ln = threadIdx.x >> 4;
    int k0 = (threadIdx.x & 15) * 4;
    int n = nodeBase + ln;
    if (n < N) {
      const uint4 u = *(const uint4*)&agg[n * HID + k0];
      aggs[ln][k0 + 0] = (u.x == ORD_NEG_INF) ? 0.f : orddec(u.x) + b2s[k0 + 0];
      aggs[ln][k0 + 1] = (u.y == ORD_NEG_INF) ? 0.f : orddec(u.y) + b2s[k0 + 1];
      aggs[ln][k0 + 2] = (u.z == ORD_NEG_INF) ? 0.f : orddec(u.z) + b2s[k0 + 2];
      aggs[ln][k0 + 3] = (u.w == ORD_NEG_INF) ? 0.f : orddec(u.w) + b2s[k0 + 3];
    }
  }
  __syncthreads();
  {
    int ln = threadIdx.x >> 4;
    int o = threadIdx.x & 15;
    int n = nodeBase + ln;
    if (n < N) {
      float acc = bos[o];
#pragma unroll
      for (int k = 0; k < HID; ++k) acc = fmaf(aggs[ln][k], Wos[k * OUTF + o], acc);
      out[n * OUTF + o] = 1.f / (1.f + __expf(-acc));
    }
  }
}

extern "C" void kernel_launch(void* const* d_in, const int* in_sizes, int n_in,
                              void* d_out, int out_size, void* d_ws, size_t ws_size,
                              hipStream_t stream) {
  const float* x  = (const float*)d_in[0];
  const int*   ei = (const int*)d_in[1];
  const float* ea = (const float*)d_in[2];
  const float* W1 = (const float*)d_in[3];
  const float* b1 = (const float*)d_in[4];
  const float* W2 = (const float*)d_in[5];
  const float* b2 = (const float*)d_in[6];
  const float* Wo = (const float*)d_in[7];
  const float* bo = (const float*)d_in[8];
  float* out = (float*)d_out;

  const int N = in_sizes[0] / IN_F;   // 50000
  const int E = in_sizes[1] / 2;      // 1600000

  // ws layout: P | Q | agg | rec (N*8*16 uint2 = 51.2MB) | cnt (N*8 i32) | ovf_cnt | ovf
  char* w = (char*)d_ws;
  float*    Pp  = (float*)w;                     w += (size_t)N * HID * 4;
  float*    Qp  = (float*)w;                     w += (size_t)N * HID * 4;
  unsigned* agg = (unsigned*)w;                  w += (size_t)N * HID * 4;
  uint2*    rec = (uint2*)w;                     w += (size_t)N * NSUB * SB_CAP * 8;
  int*      cnt = (int*)w;                       w += (size_t)N * NSUB * 4;
  int*  ovf_cnt = (int*)w;                       w += 16;
  int*      ovf = (int*)w;

  hipMemsetAsync(cnt, 0, (size_t)N * NSUB * 4 + 16, stream);

  const int nSB = (E + 1023) / 1024;   // scatter blocks (4 edges/thread)
  pre_scatter_kernel<<<nSB + 512, 256, 0, stream>>>(
      x, ei, ea, W1, b1, Pp, Qp, rec, cnt, ovf, ovf_cnt, E, N, nSB);
  bucket_kernel<<<4096, 256, 0, stream>>>(rec, cnt, W1, W2, Pp, Qp, agg, N);
  overflow_kernel<<<256, 256, 0, stream>>>(ei, ea, W1, W2, Pp, Qp, ovf, ovf_cnt, agg, E);
  out_kernel<<<(N + 15) / 16, 256, 0, stream>>>(agg, b2, Wo, bo, out, N);
}